// Round 2
// baseline (302.361 us; speedup 1.0000x reference)
//
#include <hip/hip_runtime.h>

typedef unsigned long long u64;
typedef unsigned int u32;

#define N_RECV 4096
#define N_DON  100000
#define NVEC   (N_DON / 4)   // 25000 float4 per row (100000 % 4 == 0)
#define TPB    256
#define KNN    5

__device__ __forceinline__ u64 umin64(u64 a, u64 b) { return a < b ? a : b; }
__device__ __forceinline__ u64 umax64(u64 a, u64 b) { return a < b ? b : a; }

struct T5 { u64 a, b, c, d, e; };  // sorted ascending

__device__ __forceinline__ void ce(u64 &x, u64 &y) {
    u64 lo = umin64(x, y), hi = umax64(x, y);
    x = lo; y = hi;
}

// Odd-even transposition sort, n=5 — sorts ANY input.
__device__ __forceinline__ void sort5(T5 &t) {
    ce(t.a, t.b); ce(t.c, t.d);
    ce(t.b, t.c); ce(t.d, t.e);
    ce(t.a, t.b); ce(t.c, t.d);
    ce(t.b, t.c); ce(t.d, t.e);
    ce(t.a, t.b); ce(t.c, t.d);
}

// x, y sorted ascending -> x = sorted 5 smallest of union (bitonic halver).
__device__ __forceinline__ void merge5(T5 &x, const T5 &y) {
    x.a = umin64(x.a, y.e);
    x.b = umin64(x.b, y.d);
    x.c = umin64(x.c, y.c);
    x.d = umin64(x.d, y.b);
    x.e = umin64(x.e, y.a);
    sort5(x);
}

__global__ __launch_bounds__(TPB) void knn_impute_kernel(
    const float* __restrict__ dist,   // [N_RECV, N_DON]
    const float* __restrict__ fitx,   // [N_DON]
    const int*   __restrict__ mask,   // [N_DON], 0/1
    float*       __restrict__ out)    // [N_RECV]
{
    const int row  = blockIdx.x;
    const int tid  = threadIdx.x;
    const int lane = tid & 63;
    const int wid  = tid >> 6;

    const float4* rp = reinterpret_cast<const float4*>(dist + (size_t)row * N_DON);

    // key = (float_bits(dist) << 32) | donor_idx — lexicographic (dist, idx).
    // dist in [0,1) -> non-negative -> float bits order-preserving as u32.
    u64 k0 = ~0ull, k1 = ~0ull, k2 = ~0ull, k3 = ~0ull, k4 = ~0ull;
    u32 k4hi = 0xffffffffu;   // float bits of current 5th-best (threshold)

    // Exact (dist,idx) insert; fast path below filters with u32 bits compare.
#define INSERT(DB, IDX)                                                    \
    do {                                                                   \
        u64 key = ((u64)(DB) << 32) | (u64)(IDX);                          \
        if (key < k4) {                                                    \
            if (key < k3) { k4 = k3;                                       \
                if (key < k2) { k3 = k2;                                   \
                    if (key < k1) { k2 = k1;                               \
                        if (key < k0) { k1 = k0; k0 = key; } else k1 = key;\
                    } else k2 = key;                                       \
                } else k3 = key;                                           \
            } else k4 = key;                                               \
            k4hi = (u32)(k4 >> 32);                                        \
        }                                                                  \
    } while (0)

#define PROC4(V, BASE)                                                     \
    do {                                                                   \
        u32 b0 = __float_as_uint((V).x), b1 = __float_as_uint((V).y);      \
        u32 b2 = __float_as_uint((V).z), b3 = __float_as_uint((V).w);      \
        if (b0 <= k4hi) INSERT(b0, (BASE) + 0u);                           \
        if (b1 <= k4hi) INSERT(b1, (BASE) + 1u);                           \
        if (b2 <= k4hi) INSERT(b2, (BASE) + 2u);                           \
        if (b3 <= k4hi) INSERT(b3, (BASE) + 3u);                           \
    } while (0)

    int i = tid;
    // Main loop: 4 independent float4 loads in flight (4 KB/wave of MLP).
    for (; i + 3 * TPB < NVEC; i += 4 * TPB) {
        float4 v0 = rp[i];
        float4 v1 = rp[i +     TPB];
        float4 v2 = rp[i + 2 * TPB];
        float4 v3 = rp[i + 3 * TPB];
        PROC4(v0, (u32)i * 4u);
        PROC4(v1, (u32)(i +     TPB) * 4u);
        PROC4(v2, (u32)(i + 2 * TPB) * 4u);
        PROC4(v3, (u32)(i + 3 * TPB) * 4u);
    }
    for (; i < NVEC; i += TPB) {
        float4 v = rp[i];
        PROC4(v, (u32)i * 4u);
    }

    T5 t; t.a = k0; t.b = k1; t.c = k2; t.d = k3; t.e = k4;

    // Wave butterfly allreduce.
    #pragma unroll
    for (int off = 32; off >= 1; off >>= 1) {
        T5 o;
        o.a = __shfl_xor(t.a, off);
        o.b = __shfl_xor(t.b, off);
        o.c = __shfl_xor(t.c, off);
        o.d = __shfl_xor(t.d, off);
        o.e = __shfl_xor(t.e, off);
        merge5(t, o);
    }

    // Cross-wave via tiny LDS.
    __shared__ u64 wtop[TPB / 64][KNN];
    if (lane == 0) {
        wtop[wid][0] = t.a; wtop[wid][1] = t.b; wtop[wid][2] = t.c;
        wtop[wid][3] = t.d; wtop[wid][4] = t.e;
    }
    __syncthreads();

    if (tid == 0) {
        T5 r;
        r.a = wtop[0][0]; r.b = wtop[0][1]; r.c = wtop[0][2];
        r.d = wtop[0][3]; r.e = wtop[0][4];
        #pragma unroll
        for (int w = 1; w < TPB / 64; ++w) {
            T5 o;
            o.a = wtop[w][0]; o.b = wtop[w][1]; o.c = wtop[w][2];
            o.d = wtop[w][3]; o.e = wtop[w][4];
            merge5(r, o);
        }

        // Epilogue: gather + masked mean in ascending-(dist,idx) order.
        u64 ks0 = r.a, ks1 = r.b, ks2 = r.c, ks3 = r.d, ks4 = r.e;
        float sw = 0.f, swx = 0.f;
        #pragma unroll
        for (int j = 0; j < KNN; ++j) {
            u64 key = (j == 0) ? ks0 : (j == 1) ? ks1 : (j == 2) ? ks2
                     : (j == 3) ? ks3 : ks4;
            u32 idx = (u32)(key & 0xffffffffull);
            float dv = __uint_as_float((u32)(key >> 32));
            float wm = (dv != dv) ? 0.f : 1.f;          // isnan -> 0
            float w  = (float)(1 - mask[idx]) * wm;
            sw  += w;
            swx += w * fitx[idx];
        }
        float div = (sw == 0.f) ? 1.f : sw;
        out[row] = swx / div;
    }
#undef PROC4
#undef INSERT
}

extern "C" void kernel_launch(void* const* d_in, const int* in_sizes, int n_in,
                              void* d_out, int out_size, void* d_ws, size_t ws_size,
                              hipStream_t stream) {
    const float* dist = (const float*)d_in[0];
    const float* fitx = (const float*)d_in[1];
    const int*   mask = (const int*)d_in[2];
    // d_in[3] = n_neighbors (always 5; compile-time KNN)
    float* out = (float*)d_out;

    knn_impute_kernel<<<N_RECV, TPB, 0, stream>>>(dist, fitx, mask, out);
}

// Round 3
// 267.914 us; speedup vs baseline: 1.1286x; 1.1286x over previous
//
#include <hip/hip_runtime.h>

typedef unsigned long long u64;
typedef unsigned int u32;
typedef float f32x4 __attribute__((ext_vector_type(4)));

#define N_RECV 4096
#define N_DON  100000
#define NVEC   (N_DON / 4)   // 25000 float4 per row (100000 % 4 == 0)
#define TPB    256
#define KNN    5

__device__ __forceinline__ u64 umin64(u64 a, u64 b) { return a < b ? a : b; }
__device__ __forceinline__ u64 umax64(u64 a, u64 b) { return a < b ? b : a; }

struct T5 { u64 a, b, c, d, e; };  // sorted ascending

__device__ __forceinline__ void ce(u64 &x, u64 &y) {
    u64 lo = umin64(x, y), hi = umax64(x, y);
    x = lo; y = hi;
}

// Odd-even transposition sort, n=5 — sorts ANY input.
__device__ __forceinline__ void sort5(T5 &t) {
    ce(t.a, t.b); ce(t.c, t.d);
    ce(t.b, t.c); ce(t.d, t.e);
    ce(t.a, t.b); ce(t.c, t.d);
    ce(t.b, t.c); ce(t.d, t.e);
    ce(t.a, t.b); ce(t.c, t.d);
}

// x, y sorted ascending -> x = sorted 5 smallest of union (bitonic halver).
__device__ __forceinline__ void merge5(T5 &x, const T5 &y) {
    x.a = umin64(x.a, y.e);
    x.b = umin64(x.b, y.d);
    x.c = umin64(x.c, y.c);
    x.d = umin64(x.d, y.b);
    x.e = umin64(x.e, y.a);
    sort5(x);
}

__global__ __launch_bounds__(TPB) void knn_impute_kernel(
    const float* __restrict__ dist,   // [N_RECV, N_DON]
    const float* __restrict__ fitx,   // [N_DON]
    const int*   __restrict__ mask,   // [N_DON], 0/1
    float*       __restrict__ out)    // [N_RECV]
{
    const int row  = blockIdx.x;
    const int tid  = threadIdx.x;
    const int lane = tid & 63;
    const int wid  = tid >> 6;

    const f32x4* rp = reinterpret_cast<const f32x4*>(dist + (size_t)row * N_DON);

    // key = (float_bits(dist) << 32) | donor_idx — lexicographic (dist, idx).
    // dist in [0,1) -> non-negative -> float bits order-preserving as u32.
    u64 k0 = ~0ull, k1 = ~0ull, k2 = ~0ull, k3 = ~0ull, k4 = ~0ull;
    u32 k4hi = 0xffffffffu;   // float bits of current 5th-best (threshold)

#define INSERT(DB, IDX)                                                    \
    do {                                                                   \
        u64 key = ((u64)(DB) << 32) | (u64)(IDX);                          \
        if (key < k4) {                                                    \
            if (key < k3) { k4 = k3;                                       \
                if (key < k2) { k3 = k2;                                   \
                    if (key < k1) { k2 = k1;                               \
                        if (key < k0) { k1 = k0; k0 = key; } else k1 = key;\
                    } else k2 = key;                                       \
                } else k3 = key;                                           \
            } else k4 = key;                                               \
            k4hi = (u32)(k4 >> 32);                                        \
        }                                                                  \
    } while (0)

#define PROC4(V, BASE)                                                     \
    do {                                                                   \
        u32 b0 = __float_as_uint((V).x), b1 = __float_as_uint((V).y);      \
        u32 b2 = __float_as_uint((V).z), b3 = __float_as_uint((V).w);      \
        if (b0 <= k4hi) INSERT(b0, (BASE) + 0u);                           \
        if (b1 <= k4hi) INSERT(b1, (BASE) + 1u);                           \
        if (b2 <= k4hi) INSERT(b2, (BASE) + 2u);                           \
        if (b3 <= k4hi) INSERT(b3, (BASE) + 3u);                           \
    } while (0)

    int i = tid;
    // Streaming loop: non-temporal loads — dist is read exactly once, keep
    // it out of the retain path of L1/L2/L3 (only fitx/mask benefit caches).
    for (; i + 3 * TPB < NVEC; i += 4 * TPB) {
        f32x4 v0 = __builtin_nontemporal_load(rp + i);
        f32x4 v1 = __builtin_nontemporal_load(rp + i +     TPB);
        f32x4 v2 = __builtin_nontemporal_load(rp + i + 2 * TPB);
        f32x4 v3 = __builtin_nontemporal_load(rp + i + 3 * TPB);
        PROC4(v0, (u32)i * 4u);
        PROC4(v1, (u32)(i +     TPB) * 4u);
        PROC4(v2, (u32)(i + 2 * TPB) * 4u);
        PROC4(v3, (u32)(i + 3 * TPB) * 4u);
    }
    for (; i < NVEC; i += TPB) {
        f32x4 v = __builtin_nontemporal_load(rp + i);
        PROC4(v, (u32)i * 4u);
    }

    T5 t; t.a = k0; t.b = k1; t.c = k2; t.d = k3; t.e = k4;

    // Wave butterfly allreduce.
    #pragma unroll
    for (int off = 32; off >= 1; off >>= 1) {
        T5 o;
        o.a = __shfl_xor(t.a, off);
        o.b = __shfl_xor(t.b, off);
        o.c = __shfl_xor(t.c, off);
        o.d = __shfl_xor(t.d, off);
        o.e = __shfl_xor(t.e, off);
        merge5(t, o);
    }

    // Cross-wave via tiny LDS.
    __shared__ u64 wtop[TPB / 64][KNN];
    if (lane == 0) {
        wtop[wid][0] = t.a; wtop[wid][1] = t.b; wtop[wid][2] = t.c;
        wtop[wid][3] = t.d; wtop[wid][4] = t.e;
    }
    __syncthreads();

    if (tid == 0) {
        T5 r;
        r.a = wtop[0][0]; r.b = wtop[0][1]; r.c = wtop[0][2];
        r.d = wtop[0][3]; r.e = wtop[0][4];
        #pragma unroll
        for (int w = 1; w < TPB / 64; ++w) {
            T5 o;
            o.a = wtop[w][0]; o.b = wtop[w][1]; o.c = wtop[w][2];
            o.d = wtop[w][3]; o.e = wtop[w][4];
            merge5(r, o);
        }

        // Epilogue: gather + masked mean in ascending-(dist,idx) order.
        u64 ks0 = r.a, ks1 = r.b, ks2 = r.c, ks3 = r.d, ks4 = r.e;
        float sw = 0.f, swx = 0.f;
        #pragma unroll
        for (int j = 0; j < KNN; ++j) {
            u64 key = (j == 0) ? ks0 : (j == 1) ? ks1 : (j == 2) ? ks2
                     : (j == 3) ? ks3 : ks4;
            u32 idx = (u32)(key & 0xffffffffull);
            float dv = __uint_as_float((u32)(key >> 32));
            float wm = (dv != dv) ? 0.f : 1.f;          // isnan -> 0
            float w  = (float)(1 - mask[idx]) * wm;
            sw  += w;
            swx += w * fitx[idx];
        }
        float div = (sw == 0.f) ? 1.f : sw;
        out[row] = swx / div;
    }
#undef PROC4
#undef INSERT
}

extern "C" void kernel_launch(void* const* d_in, const int* in_sizes, int n_in,
                              void* d_out, int out_size, void* d_ws, size_t ws_size,
                              hipStream_t stream) {
    const float* dist = (const float*)d_in[0];
    const float* fitx = (const float*)d_in[1];
    const int*   mask = (const int*)d_in[2];
    // d_in[3] = n_neighbors (always 5; compile-time KNN)
    float* out = (float*)d_out;

    knn_impute_kernel<<<N_RECV, TPB, 0, stream>>>(dist, fitx, mask, out);
}